// Round 8
// baseline (809.829 us; speedup 1.0000x reference)
//
#include <hip/hip_runtime.h>
#include <hip/hip_bf16.h>
#include <stdint.h>

#define N_NODES 50000
#define N_EDGES 800000
#define D 128            // D_IN == D_OUT
#define NBUK 196         // buckets of 256 nodes
#define EPB 4096         // edges per partition block
#define SEGCAP 6144      // stage capacity per bucket (avg 4082, sigma ~64)

typedef __attribute__((ext_vector_type(8))) short bf16x8;
typedef __attribute__((ext_vector_type(4))) float f32x4;
typedef __attribute__((ext_vector_type(2))) short bf16x2;

// ---- workspace layout (bytes) ----
#define FEATBF_OFF 0                 // N_NODES*128 bf16 = 12,800,000
#define STAGE_OFF  12800000          // NBUK*SEGCAP*8    =  9,633,792
#define GCUR_OFF   22433792          // NBUK i32 (memset 0), pad to 1024
#define WSW_OFF    22434816          // swizzled bf16 W  =     65,536
// total ~22.5 MB

__device__ inline short f2bf(float x) {
  union { float f; uint32_t u; } v; v.f = x;
  uint32_t r = v.u + 0x7FFFu + ((v.u >> 16) & 1u);   // RNE
  return (short)(r >> 16);
}
__device__ inline float bf2f(uint32_t bits16) {
  union { uint32_t u; float f; } v; v.u = bits16 << 16;
  return v.f;
}

// k_front: [0,3125) feat f32->bf16 ; [3125,3321) LDS-binned edge partition ;
//          [3321,3337) W swizzle
__global__ __launch_bounds__(256) void k_front(const float* __restrict__ feat,
                                               const int* __restrict__ idx,
                                               const float* __restrict__ w,
                                               const float* __restrict__ W,
                                               short* __restrict__ featbf,
                                               int* __restrict__ gcur,
                                               uint2* __restrict__ stage,
                                               short* __restrict__ wsw) {
  __shared__ uint2 lstage[EPB];      // 32 KB
  __shared__ int hist[256];
  __shared__ int pref[256];
  __shared__ int cnt2[256];
  __shared__ int gbase[256];

  int b = blockIdx.x;
  int t = threadIdx.x;

  if (b < 3125) {                    // feature convert: 8 elems/thread, exact cover
    int i = (b * 256 + t) * 8;
    f32x4 a0 = *(const f32x4*)(feat + i);
    f32x4 a1 = *(const f32x4*)(feat + i + 4);
    bf16x8 o;
    o[0] = f2bf(a0.x); o[1] = f2bf(a0.y); o[2] = f2bf(a0.z); o[3] = f2bf(a0.w);
    o[4] = f2bf(a1.x); o[5] = f2bf(a1.y); o[6] = f2bf(a1.z); o[7] = f2bf(a1.w);
    *(bf16x8*)(featbf + i) = o;
    return;
  }
  if (b >= 3125 + NBUK) {            // W swizzle (16 blocks)
    int tt = (b - 3125 - NBUK) * 256 + t;   // 0..4095
    int kstep = tt >> 9;
    int ntile = (tt >> 6) & 7;
    int lane  = tt & 63;
    int k0  = kstep * 32 + (lane >> 4) * 8;
    int col = ntile * 16 + (lane & 15);
    bf16x8 o;
    #pragma unroll
    for (int j = 0; j < 8; ++j) o[j] = f2bf(W[(k0 + j) * D + col]);
    *(bf16x8*)(wsw + tt * 8) = o;
    return;
  }

  // ---- edge partition: block bb owns edges [bb*EPB, bb*EPB+nloc) ----
  int bb = b - 3125;
  int base = bb * EPB;
  int nloc = min(EPB, N_EDGES - base);

  hist[t] = 0; cnt2[t] = 0;
  __syncthreads();

  uint32_t pay[16]; uint32_t dstv[16];
  #pragma unroll
  for (int i = 0; i < 16; ++i) {
    int s = t + i * 256;
    if (s < nloc) {
      int e = base + s;
      int dst = idx[e];
      uint32_t src = (uint32_t)idx[N_EDGES + e];
      pay[i]  = (src << 16) | ((uint32_t)f2bf(w[e]) & 0xFFFFu);
      dstv[i] = (uint32_t)dst;
      atomicAdd(&hist[dst >> 8], 1);
    }
  }
  __syncthreads();

  // exclusive scan of hist (Hillis-Steele over 256; uniform control flow)
  int v = hist[t];
  pref[t] = v;
  __syncthreads();
  #pragma unroll
  for (int off = 1; off < 256; off <<= 1) {
    int add = (t >= off) ? pref[t - off] : 0;
    __syncthreads();
    pref[t] += add;
    __syncthreads();
  }
  // reserve global range (one atomic per non-empty bucket per block)
  if (v > 0) gbase[t] = atomicAdd(&gcur[t], v);
  __syncthreads();
  pref[t] -= v;                      // make exclusive
  __syncthreads();

  // counting-sort into LDS
  #pragma unroll
  for (int i = 0; i < 16; ++i) {
    int s = t + i * 256;
    if (s < nloc) {
      int buk = (int)(dstv[i] >> 8);
      int p = atomicAdd(&cnt2[buk], 1);
      lstage[pref[buk] + p] = make_uint2(pay[i], ((uint32_t)buk << 8) | (dstv[i] & 255u));
    }
  }
  __syncthreads();

  // write out: consecutive s within a bucket -> consecutive global slots
  for (int s = t; s < nloc; s += 256) {
    uint2 vv = lstage[s];
    int buk = (int)(vv.y >> 8);
    int rel = s - pref[buk];
    stage[(size_t)buk * SEGCAP + gbase[buk] + rel] = make_uint2(vv.x, vv.y & 255u);
  }
}

// k_back: one block per bucket (256 nodes). Aggregate staged edges into LDS f32
// sums (stride 129), count degrees, then fused MFMA GEMM:
//   out[r,:] = bf16(feat[r,:]) @ W0 + bf16(sums[r,:]*invc) @ W1 + b
__global__ __launch_bounds__(1024) void k_back(const short* __restrict__ featbf,
                                               const uint2* __restrict__ stage,
                                               const int* __restrict__ gcur,
                                               const short* __restrict__ wsw,
                                               const float* __restrict__ bias,
                                               float* __restrict__ out) {
  __shared__ float sums[256 * 129];  // 132,096 B (<160 KiB); stride 129 kills GEMM-read conflicts
  __shared__ int cnt[256];

  int buk = blockIdx.x;
  int t = threadIdx.x;
  int wave = t >> 6;
  int lane = t & 63;

  for (int i = t; i < 256 * 129; i += 1024) sums[i] = 0.f;
  if (t < 256) cnt[t] = 0;
  __syncthreads();

  int len = gcur[buk];
  const uint2* seg = stage + (size_t)buk * SEGCAP;

  // aggregation: wave w processes edge chunks [4w+64k, 4w+64k+3] (exact cover)
  int i0 = wave * 4;
  for (; i0 + 3 < len; i0 += 64) {
    uint2 e0 = seg[i0 + 0];
    uint2 e1 = seg[i0 + 1];
    uint2 e2 = seg[i0 + 2];
    uint2 e3 = seg[i0 + 3];
    bf16x2 f0 = *(const bf16x2*)(featbf + (size_t)(e0.x >> 16) * D + lane * 2);
    bf16x2 f1 = *(const bf16x2*)(featbf + (size_t)(e1.x >> 16) * D + lane * 2);
    bf16x2 f2 = *(const bf16x2*)(featbf + (size_t)(e2.x >> 16) * D + lane * 2);
    bf16x2 f3 = *(const bf16x2*)(featbf + (size_t)(e3.x >> 16) * D + lane * 2);
    float w0 = bf2f(e0.x & 0xFFFFu), w1 = bf2f(e1.x & 0xFFFFu);
    float w2 = bf2f(e2.x & 0xFFFFu), w3 = bf2f(e3.x & 0xFFFFu);
    int n0 = (int)e0.y * 129 + lane * 2, n1 = (int)e1.y * 129 + lane * 2;
    int n2 = (int)e2.y * 129 + lane * 2, n3 = (int)e3.y * 129 + lane * 2;
    atomicAdd(&sums[n0 + 0], bf2f((uint16_t)f0[0]) * w0);
    atomicAdd(&sums[n0 + 1], bf2f((uint16_t)f0[1]) * w0);
    atomicAdd(&sums[n1 + 0], bf2f((uint16_t)f1[0]) * w1);
    atomicAdd(&sums[n1 + 1], bf2f((uint16_t)f1[1]) * w1);
    atomicAdd(&sums[n2 + 0], bf2f((uint16_t)f2[0]) * w2);
    atomicAdd(&sums[n2 + 1], bf2f((uint16_t)f2[1]) * w2);
    atomicAdd(&sums[n3 + 0], bf2f((uint16_t)f3[0]) * w3);
    atomicAdd(&sums[n3 + 1], bf2f((uint16_t)f3[1]) * w3);
    if (lane == 0) {
      atomicAdd(&cnt[e0.y], 1); atomicAdd(&cnt[e1.y], 1);
      atomicAdd(&cnt[e2.y], 1); atomicAdd(&cnt[e3.y], 1);
    }
  }
  #pragma unroll
  for (int j = 0; j < 4; ++j) {                    // partial last chunk (per wave)
    int ii = i0 + j;
    if (ii < len) {
      uint2 e = seg[ii];
      bf16x2 f = *(const bf16x2*)(featbf + (size_t)(e.x >> 16) * D + lane * 2);
      float wt = bf2f(e.x & 0xFFFFu);
      int n = (int)e.y * 129 + lane * 2;
      atomicAdd(&sums[n + 0], bf2f((uint16_t)f[0]) * wt);
      atomicAdd(&sums[n + 1], bf2f((uint16_t)f[1]) * wt);
      if (lane == 0) atomicAdd(&cnt[e.y], 1);
    }
  }
  __syncthreads();

  // ---- fused GEMM: wave handles 16 rows; 8 n-tiles; K=256 in 8 steps ----
  int row_l = lane & 15;
  int kq    = lane >> 4;
  int nodeA = wave * 16 + row_l;                   // local row 0..255
  int growA = buk * 256 + nodeA;                   // global row
  int growAc = min(growA, N_NODES - 1);            // clamp loads (stores guarded)
  float invc = 1.0f / fmaxf((float)cnt[nodeA], 1.0f);

  f32x4 acc[8];
  #pragma unroll
  for (int nt = 0; nt < 8; ++nt) acc[nt] = (f32x4){0.f, 0.f, 0.f, 0.f};

  #pragma unroll
  for (int kstep = 0; kstep < 8; ++kstep) {
    bf16x8 af;
    if (kstep < 4) {
      af = *(const bf16x8*)(featbf + (size_t)growAc * D + kstep * 32 + kq * 8);
    } else {
      int kk = (kstep - 4) * 32 + kq * 8;
      const float* sp = sums + nodeA * 129 + kk;
      #pragma unroll
      for (int j = 0; j < 8; ++j) af[j] = f2bf(sp[j] * invc);
    }
    const bf16x8* wrow = (const bf16x8*)(wsw + ((size_t)kstep * 8 * 64 + lane) * 8);
    #pragma unroll
    for (int nt = 0; nt < 8; ++nt) {
      bf16x8 bf = wrow[nt * 64];
      acc[nt] = __builtin_amdgcn_mfma_f32_16x16x32_bf16(af, bf, acc[nt], 0, 0, 0);
    }
  }

  // C/D layout: col = lane&15, row = (lane>>4)*4 + reg
  #pragma unroll
  for (int nt = 0; nt < 8; ++nt) {
    int col = nt * 16 + row_l;
    float bv = bias[col];
    #pragma unroll
    for (int r = 0; r < 4; ++r) {
      int orow = buk * 256 + wave * 16 + kq * 4 + r;
      if (orow < N_NODES) out[(size_t)orow * D + col] = acc[nt][r] + bv;
    }
  }
}

extern "C" void kernel_launch(void* const* d_in, const int* in_sizes, int n_in,
                              void* d_out, int out_size, void* d_ws, size_t ws_size,
                              hipStream_t stream) {
  const float* feature = (const float*)d_in[0];
  const int*   rel_idx = (const int*)d_in[1];
  const float* rel_w   = (const float*)d_in[2];
  const float* W       = (const float*)d_in[3];
  const float* b       = (const float*)d_in[4];
  float* out = (float*)d_out;

  char* ws = (char*)d_ws;
  short* featbf = (short*)(ws + FEATBF_OFF);
  uint2* stage  = (uint2*)(ws + STAGE_OFF);
  int*   gcur   = (int*)(ws + GCUR_OFF);
  short* wsw    = (short*)(ws + WSW_OFF);

  hipMemsetAsync(gcur, 0, NBUK * sizeof(int), stream);
  k_front<<<3125 + NBUK + 16, 256, 0, stream>>>(feature, rel_idx, rel_w, W,
                                                featbf, gcur, stage, wsw);
  k_back<<<NBUK, 1024, 0, stream>>>(featbf, stage, gcur, wsw, b, out);
}